// Round 15
// baseline (102.276 us; speedup 1.0000x reference)
//
#include <hip/hip_runtime.h>

#define NROWS 100000
#define IN_DIM 512

typedef __attribute__((ext_vector_type(8))) short short8;
typedef __attribute__((ext_vector_type(4))) float f32x4;

__device__ inline unsigned short f2bf(float f) {
    union { float f; unsigned u; } v; v.f = f;
    unsigned u = v.u;
    return (unsigned short)((u + 0x7FFFu + ((u >> 16) & 1u)) >> 16);
}

// Prepack: B-fragments (bf16) in exact MFMA lane order + fused que bias.
// B = [80 cols x 512 k]: cols 0..63 = Wv, 64..71 = Wq@Wk, 72..79 = 0.
// Bp layout: [t(5)][ks(16)][lane(64)][e(8)] bf16.
__global__ void qg_prepack(const float* __restrict__ Wk, const float* __restrict__ bk,
                           const float* __restrict__ Wq, const float* __restrict__ bq,
                           const float* __restrict__ Wv,
                           unsigned short* __restrict__ Bp, float* __restrict__ qb) {
    int id = blockIdx.x * 256 + threadIdx.x;  // 0..5119
    if (id < 8) {
        float s = bq[id];
        #pragma unroll 4
        for (int j = 0; j < 100; ++j) s += Wq[id * 100 + j] * bk[j];
        qb[id] = s;
    }
    if (id >= 5120) return;
    int lane = id & 63;
    int ks = (id >> 6) & 15;
    int t = id >> 10;
    int c = t * 16 + (lane & 15);
    int kk = ks * 32 + (lane >> 4) * 8;
    short8 pk;
    #pragma unroll
    for (int e = 0; e < 8; ++e) {
        int k2 = kk + e;
        float w;
        if (c < 64) {
            w = Wv[c * IN_DIM + k2];
        } else if (c < 72) {
            float s = 0.f;
            #pragma unroll 4
            for (int j = 0; j < 100; ++j) s += Wq[(c - 64) * 100 + j] * Wk[j * IN_DIM + k2];
            w = s;
        } else {
            w = 0.f;
        }
        pk[e] = (short)f2bf(w);
    }
    ((short8*)Bp)[id] = pk;
}

// Hardcoded register map (reserved via clobbers on every asm in the region):
//   A slot0 v32-63 (4 tiles x 8 f32), slot1 v64-95
//   B slot0 v96-115 (5 x dwordx4), slot1 v116-135
//   acc v136-215 (4 tiles x 5 cols x f32x4)
//   offsets v216-219 (A tiles 0..3), v220-224 (B t=0..4)
#define C32_63  "v32","v33","v34","v35","v36","v37","v38","v39","v40","v41","v42","v43","v44","v45","v46","v47","v48","v49","v50","v51","v52","v53","v54","v55","v56","v57","v58","v59","v60","v61","v62","v63"
#define C64_95  "v64","v65","v66","v67","v68","v69","v70","v71","v72","v73","v74","v75","v76","v77","v78","v79","v80","v81","v82","v83","v84","v85","v86","v87","v88","v89","v90","v91","v92","v93","v94","v95"
#define C96_135 "v96","v97","v98","v99","v100","v101","v102","v103","v104","v105","v106","v107","v108","v109","v110","v111","v112","v113","v114","v115","v116","v117","v118","v119","v120","v121","v122","v123","v124","v125","v126","v127","v128","v129","v130","v131","v132","v133","v134","v135"
#define C136_175 "v136","v137","v138","v139","v140","v141","v142","v143","v144","v145","v146","v147","v148","v149","v150","v151","v152","v153","v154","v155","v156","v157","v158","v159","v160","v161","v162","v163","v164","v165","v166","v167","v168","v169","v170","v171","v172","v173","v174","v175"
#define C176_215 "v176","v177","v178","v179","v180","v181","v182","v183","v184","v185","v186","v187","v188","v189","v190","v191","v192","v193","v194","v195","v196","v197","v198","v199","v200","v201","v202","v203","v204","v205","v206","v207","v208","v209","v210","v211","v212","v213","v214","v215"
#define C216_224 "v216","v217","v218","v219","v220","v221","v222","v223","v224"
#define CLOB C32_63, C64_95, C96_135, C136_175, C176_215, C216_224

// Issue one batch: 8 A loads (4 tiles x 2) + 5 B loads; offsets self-advance.
#define ISSUE(A0,A1,A2,A3,A4,A5,A6,A7,B0,B1,B2,B3,B4)                          \
    asm volatile(                                                              \
        "global_load_dwordx4 " A0 ", v216, %0 offset:0\n\t"                    \
        "global_load_dwordx4 " A1 ", v216, %0 offset:16\n\t"                   \
        "v_add_u32 v216, 0x80, v216\n\t"                                       \
        "global_load_dwordx4 " A2 ", v217, %0 offset:0\n\t"                    \
        "global_load_dwordx4 " A3 ", v217, %0 offset:16\n\t"                   \
        "v_add_u32 v217, 0x80, v217\n\t"                                       \
        "global_load_dwordx4 " A4 ", v218, %0 offset:0\n\t"                    \
        "global_load_dwordx4 " A5 ", v218, %0 offset:16\n\t"                   \
        "v_add_u32 v218, 0x80, v218\n\t"                                       \
        "global_load_dwordx4 " A6 ", v219, %0 offset:0\n\t"                    \
        "global_load_dwordx4 " A7 ", v219, %0 offset:16\n\t"                   \
        "v_add_u32 v219, 0x80, v219\n\t"                                       \
        "global_load_dwordx4 " B0 ", v220, %1 offset:0\n\t"                    \
        "v_add_u32 v220, 0x400, v220\n\t"                                      \
        "global_load_dwordx4 " B1 ", v221, %1 offset:0\n\t"                    \
        "v_add_u32 v221, 0x400, v221\n\t"                                      \
        "global_load_dwordx4 " B2 ", v222, %1 offset:0\n\t"                    \
        "v_add_u32 v222, 0x400, v222\n\t"                                      \
        "global_load_dwordx4 " B3 ", v223, %1 offset:0\n\t"                    \
        "v_add_u32 v223, 0x400, v223\n\t"                                      \
        "global_load_dwordx4 " B4 ", v224, %1 offset:0\n\t"                    \
        "v_add_u32 v224, 0x400, v224"                                          \
        :: "s"(x), "s"(Bp) : "memory", CLOB)

#define ISSUE0 ISSUE("v[32:35]","v[36:39]","v[40:43]","v[44:47]","v[48:51]","v[52:55]","v[56:59]","v[60:63]", \
                     "v[96:99]","v[100:103]","v[104:107]","v[108:111]","v[112:115]")
#define ISSUE1 ISSUE("v[64:67]","v[68:71]","v[72:75]","v[76:79]","v[80:83]","v[84:87]","v[88:91]","v[92:95]", \
                     "v[116:119]","v[120:123]","v[124:127]","v[128:131]","v[132:135]")

// Consume one slot: wait ladder, pack f32->bf16 in place (16 cvt), 20 MFMAs.
#define MFMA5(AF, B0,B1,B2,B3,B4, ACC0,ACC1,ACC2,ACC3,ACC4)                    \
        "v_mfma_f32_16x16x32_bf16 " ACC0 ", " AF ", " B0 ", " ACC0 "\n\t"      \
        "v_mfma_f32_16x16x32_bf16 " ACC1 ", " AF ", " B1 ", " ACC1 "\n\t"      \
        "v_mfma_f32_16x16x32_bf16 " ACC2 ", " AF ", " B2 ", " ACC2 "\n\t"      \
        "v_mfma_f32_16x16x32_bf16 " ACC3 ", " AF ", " B3 ", " ACC3 "\n\t"      \
        "v_mfma_f32_16x16x32_bf16 " ACC4 ", " AF ", " B4 ", " ACC4 "\n\t"

#define CVT4(d0,s0,s1, d1,s2,s3, d2,s4,s5, d3,s6,s7)                           \
        "v_cvt_pk_bf16_f32 " d0 ", " s0 ", " s1 "\n\t"                         \
        "v_cvt_pk_bf16_f32 " d1 ", " s2 ", " s3 "\n\t"                         \
        "v_cvt_pk_bf16_f32 " d2 ", " s4 ", " s5 "\n\t"                         \
        "v_cvt_pk_bf16_f32 " d3 ", " s6 ", " s7 "\n\t"

#define CONS0(NW)                                                              \
    asm volatile("s_waitcnt vmcnt(" NW ")" ::: "memory");                      \
    asm volatile(                                                              \
        CVT4("v32","v32","v33","v33","v34","v35","v34","v36","v37","v35","v38","v39") \
        CVT4("v40","v40","v41","v41","v42","v43","v42","v44","v45","v43","v46","v47") \
        CVT4("v48","v48","v49","v49","v50","v51","v50","v52","v53","v51","v54","v55") \
        CVT4("v56","v56","v57","v57","v58","v59","v58","v60","v61","v59","v62","v63") \
        "s_nop 1\n\t"                                                          \
        MFMA5("v[32:35]","v[96:99]","v[100:103]","v[104:107]","v[108:111]","v[112:115]", \
              "v[136:139]","v[140:143]","v[144:147]","v[148:151]","v[152:155]") \
        MFMA5("v[40:43]","v[96:99]","v[100:103]","v[104:107]","v[108:111]","v[112:115]", \
              "v[156:159]","v[160:163]","v[164:167]","v[168:171]","v[172:175]") \
        MFMA5("v[48:51]","v[96:99]","v[100:103]","v[104:107]","v[108:111]","v[112:115]", \
              "v[176:179]","v[180:183]","v[184:187]","v[188:191]","v[192:195]") \
        MFMA5("v[56:59]","v[96:99]","v[100:103]","v[104:107]","v[108:111]","v[112:115]", \
              "v[196:199]","v[200:203]","v[204:207]","v[208:211]","v[212:215]") \
        "s_nop 0" ::: "memory", CLOB)

#define CONS1(NW)                                                              \
    asm volatile("s_waitcnt vmcnt(" NW ")" ::: "memory");                      \
    asm volatile(                                                              \
        CVT4("v64","v64","v65","v65","v66","v67","v66","v68","v69","v67","v70","v71") \
        CVT4("v72","v72","v73","v73","v74","v75","v74","v76","v77","v75","v78","v79") \
        CVT4("v80","v80","v81","v81","v82","v83","v82","v84","v85","v83","v86","v87") \
        CVT4("v88","v88","v89","v89","v90","v91","v90","v92","v93","v91","v94","v95") \
        "s_nop 1\n\t"                                                          \
        MFMA5("v[64:67]","v[116:119]","v[120:123]","v[124:127]","v[128:131]","v[132:135]", \
              "v[136:139]","v[140:143]","v[144:147]","v[148:151]","v[152:155]") \
        MFMA5("v[72:75]","v[116:119]","v[120:123]","v[124:127]","v[128:131]","v[132:135]", \
              "v[156:159]","v[160:163]","v[164:167]","v[168:171]","v[172:175]") \
        MFMA5("v[80:83]","v[116:119]","v[120:123]","v[124:127]","v[128:131]","v[132:135]", \
              "v[176:179]","v[180:183]","v[184:187]","v[188:191]","v[192:195]") \
        MFMA5("v[88:91]","v[116:119]","v[120:123]","v[124:127]","v[128:131]","v[132:135]", \
              "v[196:199]","v[200:203]","v[204:207]","v[208:211]","v[212:215]") \
        "s_nop 0" ::: "memory", CLOB)

// Main: 128 threads = 2 independent waves, 64 rows/wave (4 M-tiles).
// B amortized over 64 rows -> per-CU VMEM-port bytes cut 1.7x vs R14.
// 2-deep asm ring (26 outstanding loads), vmcnt(13) ladder, NT stores.
__global__ __launch_bounds__(128, 2) void qg_main(const float* __restrict__ x,
                                                  const float* __restrict__ bv,
                                                  const unsigned short* __restrict__ Bp,
                                                  const float* __restrict__ qb,
                                                  float* __restrict__ out) {
    __shared__ float epi[2][64][76];    // per-wave [64 rows][64 val + 8 w + pad]
    const int tid = threadIdx.x;
    const int w = tid >> 6;
    const int lane = tid & 63;
    const int g = lane >> 4;
    const int cl = lane & 15;
    const int rowbase = blockIdx.x * 128 + w * 64;   // 782*128 = 100096 covers N

    unsigned voffA[4];
    #pragma unroll
    for (int m = 0; m < 4; ++m)
        voffA[m] = (unsigned)(min(rowbase + m * 16 + cl, NROWS - 1) * 512 + g * 8) * 4u;
    const unsigned voffB = (unsigned)lane * 16u;

    // Bias preload, drained before the hand-counted FIFO region.
    float bvr[4];
    #pragma unroll
    for (int t = 0; t < 4; ++t) bvr[t] = bv[t * 16 + cl];
    float qbr = qb[cl & 7];
    asm volatile("s_waitcnt vmcnt(0)" ::: "memory");

    // Init offset registers.
    asm volatile(
        "v_mov_b32 v216, %0\n\tv_mov_b32 v217, %1\n\t"
        "v_mov_b32 v218, %2\n\tv_mov_b32 v219, %3\n\t"
        "v_mov_b32 v220, %4\n\tv_mov_b32 v221, %5\n\t"
        "v_mov_b32 v222, %6\n\tv_mov_b32 v223, %7\n\t"
        "v_mov_b32 v224, %8"
        :: "v"(voffA[0]), "v"(voffA[1]), "v"(voffA[2]), "v"(voffA[3]),
           "v"(voffB), "v"(voffB + 16384u), "v"(voffB + 32768u),
           "v"(voffB + 49152u), "v"(voffB + 65536u)
        : CLOB);
    // Zero accumulators v136-215.
    {
        char zbuf[1];  (void)zbuf;
        asm volatile(
            "v_mov_b32 v136, 0\n\tv_mov_b32 v137, 0\n\tv_mov_b32 v138, 0\n\tv_mov_b32 v139, 0\n\t"
            "v_mov_b32 v140, 0\n\tv_mov_b32 v141, 0\n\tv_mov_b32 v142, 0\n\tv_mov_b32 v143, 0\n\t"
            "v_mov_b32 v144, 0\n\tv_mov_b32 v145, 0\n\tv_mov_b32 v146, 0\n\tv_mov_b32 v147, 0\n\t"
            "v_mov_b32 v148, 0\n\tv_mov_b32 v149, 0\n\tv_mov_b32 v150, 0\n\tv_mov_b32 v151, 0\n\t"
            "v_mov_b32 v152, 0\n\tv_mov_b32 v153, 0\n\tv_mov_b32 v154, 0\n\tv_mov_b32 v155, 0\n\t"
            "v_mov_b32 v156, 0\n\tv_mov_b32 v157, 0\n\tv_mov_b32 v158, 0\n\tv_mov_b32 v159, 0\n\t"
            "v_mov_b32 v160, 0\n\tv_mov_b32 v161, 0\n\tv_mov_b32 v162, 0\n\tv_mov_b32 v163, 0\n\t"
            "v_mov_b32 v164, 0\n\tv_mov_b32 v165, 0\n\tv_mov_b32 v166, 0\n\tv_mov_b32 v167, 0\n\t"
            "v_mov_b32 v168, 0\n\tv_mov_b32 v169, 0\n\tv_mov_b32 v170, 0\n\tv_mov_b32 v171, 0\n\t"
            "v_mov_b32 v172, 0\n\tv_mov_b32 v173, 0\n\tv_mov_b32 v174, 0\n\tv_mov_b32 v175, 0\n\t"
            "v_mov_b32 v176, 0\n\tv_mov_b32 v177, 0\n\tv_mov_b32 v178, 0\n\tv_mov_b32 v179, 0\n\t"
            "v_mov_b32 v180, 0\n\tv_mov_b32 v181, 0\n\tv_mov_b32 v182, 0\n\tv_mov_b32 v183, 0\n\t"
            "v_mov_b32 v184, 0\n\tv_mov_b32 v185, 0\n\tv_mov_b32 v186, 0\n\tv_mov_b32 v187, 0\n\t"
            "v_mov_b32 v188, 0\n\tv_mov_b32 v189, 0\n\tv_mov_b32 v190, 0\n\tv_mov_b32 v191, 0\n\t"
            "v_mov_b32 v192, 0\n\tv_mov_b32 v193, 0\n\tv_mov_b32 v194, 0\n\tv_mov_b32 v195, 0\n\t"
            "v_mov_b32 v196, 0\n\tv_mov_b32 v197, 0\n\tv_mov_b32 v198, 0\n\tv_mov_b32 v199, 0\n\t"
            "v_mov_b32 v200, 0\n\tv_mov_b32 v201, 0\n\tv_mov_b32 v202, 0\n\tv_mov_b32 v203, 0\n\t"
            "v_mov_b32 v204, 0\n\tv_mov_b32 v205, 0\n\tv_mov_b32 v206, 0\n\tv_mov_b32 v207, 0\n\t"
            "v_mov_b32 v208, 0\n\tv_mov_b32 v209, 0\n\tv_mov_b32 v210, 0\n\tv_mov_b32 v211, 0\n\t"
            "v_mov_b32 v212, 0\n\tv_mov_b32 v213, 0\n\tv_mov_b32 v214, 0\n\tv_mov_b32 v215, 0"
            ::: CLOB);
    }

    // Prologue: 2 batches (26 loads) in flight; steady: consume S, issue S+2.
    ISSUE0; ISSUE1;
    CONS0("13"); ISSUE0;   // S=0
    CONS1("13"); ISSUE1;   // S=1
    CONS0("13"); ISSUE0;   // S=2
    CONS1("13"); ISSUE1;   // S=3
    CONS0("13"); ISSUE0;   // S=4
    CONS1("13"); ISSUE1;   // S=5
    CONS0("13"); ISSUE0;   // S=6
    CONS1("13"); ISSUE1;   // S=7
    CONS0("13"); ISSUE0;   // S=8
    CONS1("13"); ISSUE1;   // S=9
    CONS0("13"); ISSUE0;   // S=10
    CONS1("13"); ISSUE1;   // S=11
    CONS0("13"); ISSUE0;   // S=12
    CONS1("13"); ISSUE1;   // S=13
    CONS0("13");           // S=14 (batch 15 still outstanding)
    CONS1("0");            // S=15

    // MFMA -> VALU-read hazard padding, then extract accumulators.
    asm volatile("s_nop 7\n\ts_nop 7\n\ts_nop 7");
    float ac[4][5][4];
    #define EXT(M, T, R0, R1, R2, R3)                                          \
        asm volatile("v_mov_b32 %0, " R0 "\n\tv_mov_b32 %1, " R1 "\n\t"        \
                     "v_mov_b32 %2, " R2 "\n\tv_mov_b32 %3, " R3               \
                     : "=v"(ac[M][T][0]), "=v"(ac[M][T][1]),                   \
                       "=v"(ac[M][T][2]), "=v"(ac[M][T][3]))
    EXT(0,0,"v136","v137","v138","v139"); EXT(0,1,"v140","v141","v142","v143");
    EXT(0,2,"v144","v145","v146","v147"); EXT(0,3,"v148","v149","v150","v151");
    EXT(0,4,"v152","v153","v154","v155");
    EXT(1,0,"v156","v157","v158","v159"); EXT(1,1,"v160","v161","v162","v163");
    EXT(1,2,"v164","v165","v166","v167"); EXT(1,3,"v168","v169","v170","v171");
    EXT(1,4,"v172","v173","v174","v175");
    EXT(2,0,"v176","v177","v178","v179"); EXT(2,1,"v180","v181","v182","v183");
    EXT(2,2,"v184","v185","v186","v187"); EXT(2,3,"v188","v189","v190","v191");
    EXT(2,4,"v192","v193","v194","v195");
    EXT(3,0,"v196","v197","v198","v199"); EXT(3,1,"v200","v201","v202","v203");
    EXT(3,2,"v204","v205","v206","v207"); EXT(3,4,"v212","v213","v214","v215");
    EXT(3,3,"v208","v209","v210","v211");
    #undef EXT

    // ---- Per-wave epilogue (intra-wave lockstep; lgkmcnt ordering only) ----
    // C layout: col = lane&15, row(within 16-tile) = (lane>>4)*4 + reg (m89).
    #pragma unroll
    for (int m = 0; m < 4; ++m) {
        #pragma unroll
        for (int t = 0; t < 4; ++t) {
            #pragma unroll
            for (int r = 0; r < 4; ++r)
                epi[w][m * 16 + g * 4 + r][t * 16 + cl] = ac[m][t][r] + bvr[t];
        }
        if (cl < 8) {
            #pragma unroll
            for (int r = 0; r < 4; ++r)
                epi[w][m * 16 + g * 4 + r][64 + cl] = ac[m][4][r] + qbr;
        }
    }
    asm volatile("s_waitcnt lgkmcnt(0)" ::: "memory");

    // Softmax: 64 lanes <-> 64 rows, fully parallel, no divergence.
    {
        float q[8];
        float m = -1e30f;
        #pragma unroll
        for (int k = 0; k < 8; ++k) { q[k] = epi[w][lane][64 + k]; m = fmaxf(m, q[k]); }
        float ssum = 0.f;
        #pragma unroll
        for (int k = 0; k < 8; ++k) { q[k] = __expf(q[k] - m); ssum += q[k]; }
        float inv = 1.f / ssum;
        #pragma unroll
        for (int k = 0; k < 8; ++k) epi[w][lane][64 + k] = q[k] * inv;
    }
    asm volatile("s_waitcnt lgkmcnt(0)" ::: "memory");

    // Sequential NONTEMPORAL output: out[row][k][v] = w[k]*val[v]; 1 KB/instr.
    f32x4* outp = (f32x4*)out + (size_t)rowbase * 128;
    #pragma unroll
    for (int it = 0; it < 128; ++it) {
        int idx = it * 64 + lane;
        int row = idx >> 7;             // 0..63
        int j = idx & 127;
        if (rowbase + row < NROWS) {
            float wgt = epi[w][row][64 + (j >> 4)];
            float4 vv = *(const float4*)&epi[w][row][(j & 15) * 4];
            f32x4 o;
            o[0] = wgt * vv.x; o[1] = wgt * vv.y; o[2] = wgt * vv.z; o[3] = wgt * vv.w;
            __builtin_nontemporal_store(o, &outp[(size_t)row * 128 + j]);
        }
    }
}

extern "C" void kernel_launch(void* const* d_in, const int* in_sizes, int n_in,
                              void* d_out, int out_size, void* d_ws, size_t ws_size,
                              hipStream_t stream) {
    const float* x  = (const float*)d_in[0];
    const float* Wk = (const float*)d_in[1];
    const float* bk = (const float*)d_in[2];
    const float* Wq = (const float*)d_in[3];
    const float* bq = (const float*)d_in[4];
    const float* Wv = (const float*)d_in[5];
    const float* bv = (const float*)d_in[6];
    float* out = (float*)d_out;

    unsigned short* Bp = (unsigned short*)d_ws;          // 81920 B
    float* qb = (float*)((char*)d_ws + 81920);           // 8 floats

    qg_prepack<<<20, 256, 0, stream>>>(Wk, bk, Wq, bq, Wv, Bp, qb);
    qg_main<<<782, 128, 0, stream>>>(x, bv, Bp, qb, out);
}